// Round 9
// baseline (1009.467 us; speedup 1.0000x reference)
//
#include <hip/hip_runtime.h>
#include <stdint.h>

// Sinkhorn as C = diag(u) * C0 * diag(v). One wave per node, no barriers.
// R9: bf16-packed C0 (32 dwords; numerics validated R7/R8, absmax 0.0039
// unchanged) + __launch_bounds__(256,8) for 8 waves/SIMD, with the load
// phase restructured so the compiler CANNOT hoist the full 16-load burst:
// an asm memory barrier after each pair-step caps in-flight loads at 2
// (8 VGPRs). R7/R8 proved the burst hoisting (64 dest regs) is what forced
// spilling under a <=64-reg budget; steady-state live set is only ~56.
// Occupancy steps are power-of-2 (m69): <=64 regs -> 8 waves/SIMD.
//
// Lane L owns rows {4t+(L>>4)} t=0..15, cols {4*(L&15)+k} k=0..3
// (coalesced float4 at flat 256*t + 4*L). Non-temporal loads/stores (R6).
// Row-group folds = v_add_f32 DPP row_ror; cross-row folds = shfl_xor 16/32.

#define LOG2E 1.4426950408889634f

typedef float f32x4 __attribute__((ext_vector_type(4)));

__device__ __forceinline__ float fast_rcp(float x) {
    return __builtin_amdgcn_rcpf(x);
}
__device__ __forceinline__ float fast_exp2(float x) {
    return __builtin_amdgcn_exp2f(x);
}

// DPP row rotation within each 16-lane row. ctrl 0x120+N = row_ror:N.
template<int CTRL>
__device__ __forceinline__ float row_rot(float x) {
    return __int_as_float(__builtin_amdgcn_update_dpp(
        0, __float_as_int(x), CTRL, 0xF, 0xF, true));
}
__device__ __forceinline__ float row16_allreduce_sum(float x) {
    x += row_rot<0x128>(x);
    x += row_rot<0x124>(x);
    x += row_rot<0x122>(x);
    x += row_rot<0x121>(x);
    return x;
}

// bf16 pack/unpack. pack(a,b): a -> low 16, b -> high 16, round-half-up.
__device__ __forceinline__ uint32_t pack_bf16(float a, float b) {
    uint32_t ua = (__float_as_uint(a) + 0x8000u) >> 16;
    uint32_t ub = (__float_as_uint(b) + 0x8000u) & 0xffff0000u;
    return ub | ua;
}
__device__ __forceinline__ float unpk_lo(uint32_t w) {
    return __uint_as_float(w << 16);
}
__device__ __forceinline__ float unpk_hi(uint32_t w) {
    return __uint_as_float(w & 0xffff0000u);
}

__device__ __forceinline__ float c0_of(float x) {
    x = fminf(10.0f, fmaxf(-10.0f, x));          // v_med3_f32
    float e = fast_exp2(-x * LOG2E);             // e^-x
    float s = fast_rcp(1.0f + e);                // sigmoid
    return fast_exp2(s * (100.0f * LOG2E));      // e^(s/gamma)
}

__global__ __launch_bounds__(256, 8) void sinkhorn_kernel(
    const float* __restrict__ M, float* __restrict__ out, int num_node) {

    const int wavesPerBlock = blockDim.x >> 6;
    const int node = blockIdx.x * wavesPerBlock + (threadIdx.x >> 6);
    if (node >= num_node) return;
    const int lane = threadIdx.x & 63;

    const float* __restrict__ Mn = M + (size_t)node * 4096;
    float* __restrict__ On = out + (size_t)node * 4096;

    // cp[k][tp] packs rows t=2tp (low) and t=2tp+1 (high) for column slot k.
    uint32_t cp[4][8];

    // ---- load + transform + pack, 2 rows per step, <=2 loads in flight ----
    #pragma unroll
    for (int tp = 0; tp < 8; ++tp) {
        const f32x4 va = __builtin_nontemporal_load(
            reinterpret_cast<const f32x4*>(Mn + 256 * (2 * tp) + 4 * lane));
        const f32x4 vb = __builtin_nontemporal_load(
            reinterpret_cast<const f32x4*>(Mn + 256 * (2 * tp + 1) + 4 * lane));
        #pragma unroll
        for (int k = 0; k < 4; ++k) {
            cp[k][tp] = pack_bf16(c0_of(va[k]), c0_of(vb[k]));
        }
        // compiler barrier: forbids hoisting the next pair's loads above
        // this point, capping load-phase register pressure at ~8 VGPRs.
        asm volatile("" ::: "memory");
    }

    // ---- Sinkhorn scaling vectors ----
    float u[16];
    #pragma unroll
    for (int t = 0; t < 16; ++t) u[t] = 1.0f;
    float v[4] = {1.0f, 1.0f, 1.0f, 1.0f};

    #pragma unroll
    for (int it = 0; it < 5; ++it) {
        // column sums: d_j = sum_i u_i * C0[i,j]
        #pragma unroll
        for (int k = 0; k < 4; ++k) {
            float acc = 0.0f;
            #pragma unroll
            for (int tp = 0; tp < 8; ++tp) {
                const uint32_t w = cp[k][tp];
                acc = fmaf(u[2 * tp],     unpk_lo(w), acc);
                acc = fmaf(u[2 * tp + 1], unpk_hi(w), acc);
            }
            acc += __shfl_xor(acc, 16, 64);   // fold the 4 row-groups
            acc += __shfl_xor(acc, 32, 64);
            v[k] = fast_rcp(acc);
        }
        // row sums: e_i = sum_j C0[i,j] * v_j  (two rows per packed word)
        #pragma unroll
        for (int tp = 0; tp < 8; ++tp) {
            float a0 = 0.0f, a1 = 0.0f;
            #pragma unroll
            for (int k = 0; k < 4; ++k) {
                const uint32_t w = cp[k][tp];
                a0 = fmaf(unpk_lo(w), v[k], a0);
                a1 = fmaf(unpk_hi(w), v[k], a1);
            }
            u[2 * tp]     = fast_rcp(row16_allreduce_sum(a0));
            u[2 * tp + 1] = fast_rcp(row16_allreduce_sum(a1));
        }
    }

    // ---- write out = u_i * C0[i,j] * v_j, non-temporal 16B stores ----
    #pragma unroll
    for (int tp = 0; tp < 8; ++tp) {
        f32x4 o0, o1;
        #pragma unroll
        for (int k = 0; k < 4; ++k) {
            const uint32_t w = cp[k][tp];
            o0[k] = u[2 * tp]     * unpk_lo(w) * v[k];
            o1[k] = u[2 * tp + 1] * unpk_hi(w) * v[k];
        }
        __builtin_nontemporal_store(o0,
            reinterpret_cast<f32x4*>(On + 256 * (2 * tp) + 4 * lane));
        __builtin_nontemporal_store(o1,
            reinterpret_cast<f32x4*>(On + 256 * (2 * tp + 1) + 4 * lane));
    }
}

extern "C" void kernel_launch(void* const* d_in, const int* in_sizes, int n_in,
                              void* d_out, int out_size, void* d_ws, size_t ws_size,
                              hipStream_t stream) {
    const float* M = (const float*)d_in[0];
    float* out = (float*)d_out;
    const int num_node = in_sizes[0] / 4096;   // 64*64 per node

    const int wavesPerBlock = 4;               // 256 threads
    const int blocks = (num_node + wavesPerBlock - 1) / wavesPerBlock;
    sinkhorn_kernel<<<blocks, 256, 0, stream>>>(M, out, num_node);
}

// Round 10
// 294.710 us; speedup vs baseline: 3.4253x; 3.4253x over previous
//
#include <hip/hip_runtime.h>

// Sinkhorn iteration factored as C = diag(u) * C0 * diag(v).
// One wave (64 lanes) per node, no barriers. Lane L owns a 16x4 subtile:
//   rows {4t + (L>>4)}, t=0..15 ; cols {4*(L&15)+k}, k=0..3
// (ownership induced by coalesced float4 loads at flat index 256*t + 4*L).
//
// FINAL (R6 revert): this is the verified 292.7us / 5.6 TB/s configuration.
// - Non-temporal 16B loads/stores: touch-once stream, L2 no-retain (-27us, R6).
// - HW transcendentals (v_exp_f32/v_rcp_f32) for sigmoid/exp/divides (-98us, R2).
// - DPP row_ror folds for the 16-lane row reduction (VALU pipe, -5us, R4).
// Closed levers (all regressed):
// - Multi-wave/node with LDS exchange: barriers align phases (R3: 348us).
// - 8 waves/SIMD via <=64 VGPR: live set cp32+u16+v4+temps can't fit;
//   compiler spills to scratch 3 ways (R7: 978us, R8: 628us, R9: 1009us).
//   Occupancy steps are power-of-2: no 5/6-wave middle ground exists.
// Operating point: 89% of the measured R+W copy ceiling (6.29 TB/s, m13).

#define LOG2E 1.4426950408889634f

typedef float f32x4 __attribute__((ext_vector_type(4)));

__device__ __forceinline__ float fast_rcp(float x) {
    return __builtin_amdgcn_rcpf(x);
}
__device__ __forceinline__ float fast_exp2(float x) {
    return __builtin_amdgcn_exp2f(x);
}

// DPP row rotation within each 16-lane row (gfx9 DPP: row = 16 lanes).
// ctrl 0x120+N = row_ror:N. bound_ctrl=1, full row/bank masks.
template<int CTRL>
__device__ __forceinline__ float row_rot(float x) {
    return __int_as_float(__builtin_amdgcn_update_dpp(
        0, __float_as_int(x), CTRL, 0xF, 0xF, true));
}

// Sum all-reduce across each 16-lane row via rotations 8,4,2,1.
__device__ __forceinline__ float row16_allreduce_sum(float x) {
    x += row_rot<0x128>(x);   // + ror 8
    x += row_rot<0x124>(x);   // + ror 4
    x += row_rot<0x122>(x);   // + ror 2
    x += row_rot<0x121>(x);   // + ror 1
    return x;                 // every lane holds the row-of-16 sum
}

__global__ __launch_bounds__(256) void sinkhorn_kernel(
    const float* __restrict__ M, float* __restrict__ out, int num_node) {

    const int wavesPerBlock = blockDim.x >> 6;
    const int node = blockIdx.x * wavesPerBlock + (threadIdx.x >> 6);
    if (node >= num_node) return;
    const int lane = threadIdx.x & 63;

    const float* __restrict__ Mn = M + (size_t)node * 4096;
    float* __restrict__ On = out + (size_t)node * 4096;

    // ---- load 64x64 tile, non-temporal 16B loads, fully coalesced ----
    float c[16][4];
    #pragma unroll
    for (int t = 0; t < 16; ++t) {
        const f32x4 val = __builtin_nontemporal_load(
            reinterpret_cast<const f32x4*>(Mn + 256 * t + 4 * lane));
        c[t][0] = val.x; c[t][1] = val.y; c[t][2] = val.z; c[t][3] = val.w;
    }

    // ---- C0 = exp(sigmoid(clamp(M,-10,10)) / 0.01) via v_exp/v_rcp ----
    #pragma unroll
    for (int t = 0; t < 16; ++t) {
        #pragma unroll
        for (int k = 0; k < 4; ++k) {
            float x = c[t][k];
            x = fminf(10.0f, fmaxf(-10.0f, x));          // v_med3_f32
            float e = fast_exp2(-x * LOG2E);             // e^-x
            float s = fast_rcp(1.0f + e);                // sigmoid
            c[t][k] = fast_exp2(s * (100.0f * LOG2E));   // e^(s/gamma)
        }
    }

    // ---- Sinkhorn scaling vectors ----
    float u[16];
    #pragma unroll
    for (int t = 0; t < 16; ++t) u[t] = 1.0f;
    float v[4] = {1.0f, 1.0f, 1.0f, 1.0f};

    #pragma unroll
    for (int it = 0; it < 5; ++it) {
        // column sums: d_j = sum_i u_i * C0[i,j]   (fold rows: lane-local
        // over t, then across the 4 row-groups = lanes differing in bits 4,5)
        float d[4];
        #pragma unroll
        for (int k = 0; k < 4; ++k) {
            float acc = 0.0f;
            #pragma unroll
            for (int t = 0; t < 16; ++t) acc = fmaf(u[t], c[t][k], acc);
            d[k] = acc;
        }
        #pragma unroll
        for (int k = 0; k < 4; ++k) {
            d[k] += __shfl_xor(d[k], 16, 64);
            d[k] += __shfl_xor(d[k], 32, 64);
            v[k] = fast_rcp(d[k]);
        }
        // row sums: e_i = sum_j C0[i,j] * v_j  (fold cols: lane-local over k,
        // then all-reduce across the 16-lane row via DPP rotations)
        #pragma unroll
        for (int t = 0; t < 16; ++t) {
            float acc = 0.0f;
            #pragma unroll
            for (int k = 0; k < 4; ++k) acc = fmaf(c[t][k], v[k], acc);
            u[t] = fast_rcp(row16_allreduce_sum(acc));
        }
    }

    // ---- write out = u_i * C0[i,j] * v_j, non-temporal 16B stores ----
    #pragma unroll
    for (int t = 0; t < 16; ++t) {
        f32x4 o;
        o.x = u[t] * c[t][0] * v[0];
        o.y = u[t] * c[t][1] * v[1];
        o.z = u[t] * c[t][2] * v[2];
        o.w = u[t] * c[t][3] * v[3];
        __builtin_nontemporal_store(o, reinterpret_cast<f32x4*>(On + 256 * t + 4 * lane));
    }
}

extern "C" void kernel_launch(void* const* d_in, const int* in_sizes, int n_in,
                              void* d_out, int out_size, void* d_ws, size_t ws_size,
                              hipStream_t stream) {
    const float* M = (const float*)d_in[0];
    float* out = (float*)d_out;
    const int num_node = in_sizes[0] / 4096;   // 64*64 per node

    const int wavesPerBlock = 4;               // 256 threads
    const int blocks = (num_node + wavesPerBlock - 1) / wavesPerBlock;
    sinkhorn_kernel<<<blocks, 256, 0, stream>>>(M, out, num_node);
}